// Round 4
// baseline (389.990 us; speedup 1.0000x reference)
//
#include <hip/hip_runtime.h>
#include <math.h>

// SplineConv x2 (K=4, dim=1, degree=1, mean aggr) + ELU + log_softmax.
// R10: fp8 table (R9) was neutral (+1.7us) and cost accuracy -> reverted
// to bf16 agg1 (R8 form). The bucketed sort (bucket_hist/mini_scan/
// bucket_scatter/node_sort) ran at 0.8-1.5 blocks/CU with ~20 barrier
// phases each and 38MB of tpd traffic -- but edge ORDER within a node is
// irrelevant for a sum. Replaced with a direct counting sort:
//   deg histogram (global atomics, 50K L2-resident counters)
//   -> 3 tiny coalesced scan kernels -> one 6250-block scatter
//      spk[atomicAdd(&cur[dst],1)] = spl.
// tpd eliminated; no workspace aliasing constraints on xw1 anymore.

#define F_IN   48
#define HID    32
#define NCLS   10
#define KS     4

__device__ inline unsigned short f2bf(float f) {
    unsigned x = __float_as_uint(f);
    unsigned r = x + 0x7FFFu + ((x >> 16) & 1u);  // RNE
    return (unsigned short)(r >> 16);
}
__device__ inline float bf2f(unsigned short u) {
    return __uint_as_float(((unsigned)u) << 16);
}

// ---------- CSR build (counting sort, order-free within node) ----------

__global__ void deg_hist_kernel(const int* __restrict__ ei, int* __restrict__ deg, int E) {
    int i = blockIdx.x * blockDim.x + threadIdx.x;
    if (i < E) atomicAdd(&deg[ei[E + i]], 1);
}

// block sums of deg (256 values per block)
__global__ void scan_a_kernel(const int* __restrict__ deg, int* __restrict__ bsum, int N) {
    int i = blockIdx.x * 256 + threadIdx.x;
    int t = threadIdx.x;
    int v = (i < N) ? deg[i] : 0;
#pragma unroll
    for (int m = 1; m < 64; m <<= 1) v += __shfl_xor(v, m, 64);
    __shared__ int red[4];
    if ((t & 63) == 0) red[t >> 6] = v;
    __syncthreads();
    if (t == 0) bsum[blockIdx.x] = red[0] + red[1] + red[2] + red[3];
}

// exclusive scan of <=256 block sums
__global__ void scan_b_kernel(const int* __restrict__ bsum, int* __restrict__ bbase, int nb) {
    __shared__ int a[256];
    int t = threadIdx.x;
    int v = (t < nb) ? bsum[t] : 0;
    a[t] = v;
    __syncthreads();
    for (int o = 1; o < 256; o <<= 1) {
        int w = (t >= o) ? a[t - o] : 0;
        __syncthreads();
        a[t] += w;
        __syncthreads();
    }
    if (t < nb) bbase[t] = a[t] - v;
}

// per-block exclusive prefix + base -> offs, cur
__global__ void scan_c_kernel(const int* __restrict__ deg, const int* __restrict__ bbase,
                              int* __restrict__ offs, int* __restrict__ cur, int N, int E) {
    __shared__ int a[256];
    int t = threadIdx.x;
    int i = blockIdx.x * 256 + t;
    int v = (i < N) ? deg[i] : 0;
    a[t] = v;
    __syncthreads();
    for (int o = 1; o < 256; o <<= 1) {
        int w = (t >= o) ? a[t - o] : 0;
        __syncthreads();
        a[t] += w;
        __syncthreads();
    }
    int ex = bbase[blockIdx.x] + a[t] - v;
    if (i < N) { offs[i] = ex; cur[i] = ex; }
    if (i == N - 1) offs[N] = E;
}

__global__ void edge_scatter_kernel(const int* __restrict__ ei, const float* __restrict__ ea,
                                    int* __restrict__ cur, unsigned* __restrict__ spk, int E) {
    int i = blockIdx.x * blockDim.x + threadIdx.x;
    if (i >= E) return;
    int src = ei[i];
    int dst = ei[E + i];
    float u = ea[i];
    float v = u * (float)(KS - 1);
    float vf = floorf(v);
    int k0 = min(max((int)vf, 0), KS - 1);
    unsigned qf = (unsigned)((v - vf) * 16383.f + 0.5f);  // 14-bit frac
    unsigned spl = (unsigned)src | ((unsigned)k0 << 16) | (qf << 18);
    int pos = atomicAdd(&cur[dst], 1);
    spk[pos] = spl;
}

// ---------- xw tables (LDS-staged W, register-blocked) ----------

__global__ __launch_bounds__(320) void xw1_kernel(
        const float* __restrict__ X, const float* __restrict__ W,
        const float* __restrict__ R, unsigned short* __restrict__ outk,
        float* __restrict__ outr, int n) {
    __shared__ float lw[48 * 160];
    int t = threadIdx.x;
    for (int i = t; i < 48 * 160; i += 320) {
        int f = i / 160;
        int col = i - f * 160;
        lw[i] = (col < 128) ? W[(size_t)(col >> 5) * (48 * 32) + f * 32 + (col & 31)]
                            : R[f * 32 + (col - 128)];
    }
    __syncthreads();
    int g = t % 40;      // colgroup (4 cols)
    int lp = t / 40;     // local pair 0..7
    int n0 = (blockIdx.x * 8 + lp) * 2;
    if (n0 + 1 >= n) return;
    const float4* X0 = (const float4*)(X + (size_t)n0 * F_IN);
    const float4* X1 = (const float4*)(X + (size_t)(n0 + 1) * F_IN);
    float4 x0[12], x1[12];
#pragma unroll
    for (int i = 0; i < 12; ++i) { x0[i] = X0[i]; x1[i] = X1[i]; }
    const float4* lw4 = (const float4*)lw;  // lw4[f*40 + g]
    float4 a0 = {0,0,0,0}, a1 = {0,0,0,0};
#pragma unroll
    for (int fb = 0; fb < 12; ++fb) {
        float4 v0 = x0[fb], v1 = x1[fb];
#pragma unroll
        for (int j = 0; j < 4; ++j) {
            float s0 = (j == 0) ? v0.x : (j == 1) ? v0.y : (j == 2) ? v0.z : v0.w;
            float s1 = (j == 0) ? v1.x : (j == 1) ? v1.y : (j == 2) ? v1.z : v1.w;
            float4 w = lw4[(fb * 4 + j) * 40 + g];
            a0.x = fmaf(s0, w.x, a0.x); a0.y = fmaf(s0, w.y, a0.y);
            a0.z = fmaf(s0, w.z, a0.z); a0.w = fmaf(s0, w.w, a0.w);
            a1.x = fmaf(s1, w.x, a1.x); a1.y = fmaf(s1, w.y, a1.y);
            a1.z = fmaf(s1, w.z, a1.z); a1.w = fmaf(s1, w.w, a1.w);
        }
    }
    if (g < 32) {
        uint2 u0, u1;
        u0.x = f2bf(a0.x) | ((unsigned)f2bf(a0.y) << 16);
        u0.y = f2bf(a0.z) | ((unsigned)f2bf(a0.w) << 16);
        u1.x = f2bf(a1.x) | ((unsigned)f2bf(a1.y) << 16);
        u1.y = f2bf(a1.z) | ((unsigned)f2bf(a1.w) << 16);
        *(uint2*)(outk + (size_t)n0 * (KS * HID) + g * 4) = u0;
        *(uint2*)(outk + (size_t)(n0 + 1) * (KS * HID) + g * 4) = u1;
    } else {
        int o = 4 * g - 128;
        *(float4*)(outr + (size_t)n0 * HID + o) = a0;
        *(float4*)(outr + (size_t)(n0 + 1) * HID + o) = a1;
    }
}

__global__ void xw2_kernel(const float* __restrict__ H, const float* __restrict__ W,
                           const float* __restrict__ R, unsigned short* __restrict__ outk,
                           float* __restrict__ outr, int n) {
    __shared__ float lw2[32 * 50];
    int t = threadIdx.x;
    for (int i = t; i < 32 * 50; i += 256) {
        int f = i / 50;
        int col = i - f * 50;
        lw2[i] = (col < 40) ? W[(size_t)(col / 10) * (32 * 10) + f * 10 + (col % 10)]
                            : R[f * 10 + (col - 40)];
    }
    __syncthreads();
    int total = (n / 2) * 25;
    int id = blockIdx.x * blockDim.x + t;
    if (id >= total) return;
    int p = id % 25;
    int pr = id / 25;
    int n0 = 2 * pr;
    const float4* H0 = (const float4*)(H + (size_t)n0 * HID);
    const float4* H1 = (const float4*)(H + (size_t)(n0 + 1) * HID);
    float4 h0[8], h1[8];
#pragma unroll
    for (int i = 0; i < 8; ++i) { h0[i] = H0[i]; h1[i] = H1[i]; }
    const float2* lwp = (const float2*)lw2;  // lwp[f*25 + p]
    float ax0 = 0.f, ay0 = 0.f, ax1 = 0.f, ay1 = 0.f;
#pragma unroll
    for (int fb = 0; fb < 8; ++fb) {
        float4 v0 = h0[fb], v1 = h1[fb];
#pragma unroll
        for (int j = 0; j < 4; ++j) {
            float s0 = (j == 0) ? v0.x : (j == 1) ? v0.y : (j == 2) ? v0.z : v0.w;
            float s1 = (j == 0) ? v1.x : (j == 1) ? v1.y : (j == 2) ? v1.z : v1.w;
            float2 w = lwp[(fb * 4 + j) * 25 + p];
            ax0 = fmaf(s0, w.x, ax0); ay0 = fmaf(s0, w.y, ay0);
            ax1 = fmaf(s1, w.x, ax1); ay1 = fmaf(s1, w.y, ay1);
        }
    }
    int col = 2 * p;
    if (col < KS * NCLS) {
        *(unsigned*)(outk + (size_t)n0 * (KS * NCLS) + col) =
            f2bf(ax0) | ((unsigned)f2bf(ay0) << 16);
        *(unsigned*)(outk + (size_t)(n0 + 1) * (KS * NCLS) + col) =
            f2bf(ax1) | ((unsigned)f2bf(ay1) << 16);
    } else {
        int o = col - KS * NCLS;
        *(float2*)(outr + (size_t)n0 * NCLS + o) = make_float2(ax0, ay0);
        *(float2*)(outr + (size_t)(n0 + 1) * NCLS + o) = make_float2(ax1, ay1);
    }
}

// ---------- aggregation ----------

// Decode a packed spline record into a row pointer, k1-k0 offset, frac.
#define DECODE32(p, row, dk, fr)                                          \
    {   int src_ = (p) & 0xFFFF;                                          \
        int k0_ = ((p) >> 16) & 3;                                        \
        int k1_ = min(k0_ + 1, KS - 1);                                   \
        fr = (float)((p) >> 18) * (1.f / 16383.f);                        \
        row = xwk + (size_t)src_ * (KS * HID) + k0_ * HID + cg * 4;       \
        dk = (k1_ - k0_) * HID; }

__device__ inline void fma4(uint2 v0, uint2 v1, float fr, float4& a) {
    float w0 = 1.f - fr;
    a.x = fmaf(w0, __uint_as_float(v0.x << 16), a.x);
    a.x = fmaf(fr, __uint_as_float(v1.x << 16), a.x);
    a.y = fmaf(w0, __uint_as_float(v0.x & 0xFFFF0000u), a.y);
    a.y = fmaf(fr, __uint_as_float(v1.x & 0xFFFF0000u), a.y);
    a.z = fmaf(w0, __uint_as_float(v0.y << 16), a.z);
    a.z = fmaf(fr, __uint_as_float(v1.y << 16), a.z);
    a.w = fmaf(w0, __uint_as_float(v0.y & 0xFFFF0000u), a.w);
    a.w = fmaf(fr, __uint_as_float(v1.y & 0xFFFF0000u), a.w);
}

// agg1: one wave per node; lane = (slot 0..7, chgroup 0..7). Quad-unrolled:
// 32 edges (64 row-gathers) in flight per wave.
__global__ void agg1_kernel(const unsigned short* __restrict__ xwk,
                            const float* __restrict__ xroot,
                            const int* __restrict__ offs, const unsigned* __restrict__ spk,
                            const float* __restrict__ bias, float* __restrict__ h, int n) {
    int lane = threadIdx.x & 63;
    int cg = lane & 7;       // channels 4cg..4cg+3
    int slot = lane >> 3;    // 8 edge slots
    int node = blockIdx.x * 4 + (threadIdx.x >> 6);
    if (node >= n) return;
    int beg = offs[node];
    int end = offs[node + 1];
    float4 a0 = {0, 0, 0, 0}, a1 = {0, 0, 0, 0};
    int e = beg + slot;
    while (e + 24 < end) {
        unsigned p0 = spk[e], p1 = spk[e + 8], p2 = spk[e + 16], p3 = spk[e + 24];
        const unsigned short *r0, *r1, *r2, *r3;
        int d0, d1, d2, d3;
        float f0, f1, f2, f3;
        DECODE32(p0, r0, d0, f0);
        DECODE32(p1, r1, d1, f1);
        DECODE32(p2, r2, d2, f2);
        DECODE32(p3, r3, d3, f3);
        uint2 v00 = *(const uint2*)r0, v01 = *(const uint2*)(r0 + d0);
        uint2 v10 = *(const uint2*)r1, v11 = *(const uint2*)(r1 + d1);
        uint2 v20 = *(const uint2*)r2, v21 = *(const uint2*)(r2 + d2);
        uint2 v30 = *(const uint2*)r3, v31 = *(const uint2*)(r3 + d3);
        fma4(v00, v01, f0, a0);
        fma4(v10, v11, f1, a1);
        fma4(v20, v21, f2, a0);
        fma4(v30, v31, f3, a1);
        e += 32;
    }
    while (e < end) {
        unsigned p = spk[e];
        const unsigned short* r;
        int d;
        float f;
        DECODE32(p, r, d, f);
        uint2 v0 = *(const uint2*)r, v1 = *(const uint2*)(r + d);
        fma4(v0, v1, f, a0);
        e += 8;
    }
    float4 s;
    s.x = a0.x + a1.x; s.y = a0.y + a1.y; s.z = a0.z + a1.z; s.w = a0.w + a1.w;
#pragma unroll
    for (int m = 8; m < 64; m <<= 1) {   // reduce across 8 slots
        s.x += __shfl_xor(s.x, m, 64);
        s.y += __shfl_xor(s.y, m, 64);
        s.z += __shfl_xor(s.z, m, 64);
        s.w += __shfl_xor(s.w, m, 64);
    }
    if (slot == 0) {
        int deg = end - beg;
        float inv = 1.f / (float)(deg > 0 ? deg : 1);
        float4 r = *(const float4*)(xroot + (size_t)node * HID + cg * 4);
        float4 b = *(const float4*)(bias + cg * 4);
        float4 o;
        o.x = fmaf(s.x, inv, r.x + b.x);
        o.y = fmaf(s.y, inv, r.y + b.y);
        o.z = fmaf(s.z, inv, r.z + b.z);
        o.w = fmaf(s.w, inv, r.w + b.w);
        o.x = (o.x > 0.f) ? o.x : expm1f(o.x);
        o.y = (o.y > 0.f) ? o.y : expm1f(o.y);
        o.z = (o.z > 0.f) ? o.z : expm1f(o.z);
        o.w = (o.w > 0.f) ? o.w : expm1f(o.w);
        *(float4*)(h + (size_t)node * HID + cg * 4) = o;
    }
}

#define DECODE10(p, row, dk, fr)                                          \
    {   int src_ = (p) & 0xFFFF;                                          \
        int k0_ = ((p) >> 16) & 3;                                        \
        int k1_ = min(k0_ + 1, KS - 1);                                   \
        fr = (float)((p) >> 18) * (1.f / 16383.f);                        \
        row = xwk + (size_t)src_ * (KS * NCLS) + k0_ * NCLS + cc;         \
        dk = (k1_ - k0_) * NCLS; }

// agg2: one wave per node; lane = (slot 0..3, channel16). Quad-unrolled:
// 16 edges in flight per wave.
__global__ void agg2_kernel(const unsigned short* __restrict__ xwk,
                            const float* __restrict__ xroot,
                            const int* __restrict__ offs, const unsigned* __restrict__ spk,
                            const float* __restrict__ bias, float* __restrict__ out, int n) {
    int lane = threadIdx.x & 63;
    int c = lane & 15;
    int slot = lane >> 4;    // 4 edge slots
    int node = blockIdx.x * 4 + (threadIdx.x >> 6);
    if (node >= n) return;
    int cc = min(c, NCLS - 1);
    int beg = offs[node];
    int end = offs[node + 1];
    float s0 = 0.f, s1 = 0.f;
    int e = beg + slot;
    while (e + 12 < end) {
        unsigned p0 = spk[e], p1 = spk[e + 4], p2 = spk[e + 8], p3 = spk[e + 12];
        const unsigned short *r0, *r1, *r2, *r3;
        int d0, d1, d2, d3;
        float f0, f1, f2, f3;
        DECODE10(p0, r0, d0, f0);
        DECODE10(p1, r1, d1, f1);
        DECODE10(p2, r2, d2, f2);
        DECODE10(p3, r3, d3, f3);
        unsigned short a00 = r0[0], a01 = r0[d0];
        unsigned short a10 = r1[0], a11 = r1[d1];
        unsigned short a20 = r2[0], a21 = r2[d2];
        unsigned short a30 = r3[0], a31 = r3[d3];
        float x00 = bf2f(a00), x01 = bf2f(a01);
        float x10 = bf2f(a10), x11 = bf2f(a11);
        float x20 = bf2f(a20), x21 = bf2f(a21);
        float x30 = bf2f(a30), x31 = bf2f(a31);
        s0 += fmaf(f0, x01 - x00, x00);
        s1 += fmaf(f1, x11 - x10, x10);
        s0 += fmaf(f2, x21 - x20, x20);
        s1 += fmaf(f3, x31 - x30, x30);
        e += 16;
    }
    while (e < end) {
        unsigned p = spk[e];
        const unsigned short* r;
        int d;
        float f;
        DECODE10(p, r, d, f);
        float x0 = bf2f(r[0]), x1 = bf2f(r[d]);
        s0 += fmaf(f, x1 - x0, x0);
        e += 4;
    }
    float sum = s0 + s1;
    sum += __shfl_xor(sum, 16, 64);  // merge 4 slots
    sum += __shfl_xor(sum, 32, 64);
    int deg = end - beg;
    float m = sum / (float)(deg > 0 ? deg : 1);
    float logit = m + xroot[(size_t)node * NCLS + cc] + bias[cc];
    bool active = (c < NCLS);
    float mx = active ? logit : -INFINITY;
#pragma unroll
    for (int msk = 1; msk < 16; msk <<= 1) mx = fmaxf(mx, __shfl_xor(mx, msk, 16));
    float ex = active ? expf(logit - mx) : 0.f;
    float s = ex;
#pragma unroll
    for (int msk = 1; msk < 16; msk <<= 1) s += __shfl_xor(s, msk, 16);
    if (active && slot == 0) out[(size_t)node * NCLS + c] = (logit - mx) - logf(s);
}

extern "C" void kernel_launch(void* const* d_in, const int* in_sizes, int n_in,
                              void* d_out, int out_size, void* d_ws, size_t ws_size,
                              hipStream_t stream) {
    const float* x       = (const float*)d_in[0];
    const int*   ei      = (const int*)d_in[1];
    const float* ea      = (const float*)d_in[2];
    const float* W1      = (const float*)d_in[3];
    const float* root1   = (const float*)d_in[4];
    const float* bias1   = (const float*)d_in[5];
    const float* W2      = (const float*)d_in[6];
    const float* root2   = (const float*)d_in[7];
    const float* bias2   = (const float*)d_in[8];
    float* out = (float*)d_out;

    const int N = in_sizes[0] / F_IN;      // 50000
    const int E = in_sizes[2];             // 1600000
    const int NBLK = (N + 255) >> 8;       // 196 scan blocks

    char* base = (char*)d_ws;
    size_t off = 0;
    auto alloc = [&](size_t bytes) {
        char* p = base + off;
        off = (off + bytes + 255) & ~(size_t)255;
        return (void*)p;
    };
    unsigned short* xwk1 = (unsigned short*)alloc((size_t)N * KS * HID * 2); // 12.8 MB
    float* xr1           = (float*)alloc((size_t)N * HID * 4);               // 6.4 MB
    float* h             = (float*)alloc((size_t)N * HID * 4);               // 6.4 MB
    int* offs            = (int*)alloc(((size_t)N + 1) * 4);
    int* deg             = (int*)alloc((size_t)N * 4);
    int* cur             = (int*)alloc((size_t)N * 4);
    int* bsum            = (int*)alloc((size_t)NBLK * 4);
    int* bbase           = (int*)alloc((size_t)NBLK * 4);
    unsigned* spk        = (unsigned*)alloc((size_t)E * 4);                  // 6.4 MB
    unsigned short* xwk2 = xwk1;   // 4MB bf16, overwritten after agg1
    float* xr2           = xr1;
    if (ws_size < off) return;

    hipMemsetAsync(deg, 0, (size_t)N * 4, stream);
    deg_hist_kernel<<<(E + 255) / 256, 256, 0, stream>>>(ei, deg, E);
    scan_a_kernel<<<NBLK, 256, 0, stream>>>(deg, bsum, N);
    scan_b_kernel<<<1, 256, 0, stream>>>(bsum, bbase, NBLK);
    scan_c_kernel<<<NBLK, 256, 0, stream>>>(deg, bbase, offs, cur, N, E);
    edge_scatter_kernel<<<(E + 255) / 256, 256, 0, stream>>>(ei, ea, cur, spk, E);
    xw1_kernel<<<(N + 15) / 16, 320, 0, stream>>>(x, W1, root1, xwk1, xr1, N);
    agg1_kernel<<<(N + 3) / 4, 256, 0, stream>>>(xwk1, xr1, offs, spk, bias1, h, N);
    {
        int total = (N / 2) * 25;
        xw2_kernel<<<(total + 255) / 256, 256, 0, stream>>>(h, W2, root2, xwk2, xr2, N);
    }
    agg2_kernel<<<(N + 3) / 4, 256, 0, stream>>>(xwk2, xr2, offs, spk, bias2, out, N);
}

// Round 5
// 258.376 us; speedup vs baseline: 1.5094x; 1.5094x over previous
//
#include <hip/hip_runtime.h>
#include <math.h>

// SplineConv x2 (K=4, dim=1, degree=1, mean aggr) + ELU + log_softmax.
// R11: R10's counting sort regressed 250->390us (edge_scatter 130us:
// 1.6M random 4B stores = 100MB RMW traffic @0.86TB/s + atomic-return
// serialization). Reverted to R8's bucketed CSR build -- which the R10
// delta proves costs ~0-10us total. New cuts:
//  (a) xw2 fused into agg1's epilogue: every lane holds 4 h-channels
//      after the slot-reduce; ELU on all lanes, wave-broadcast h via 32
//      static shfl, dot vs LDS-staged W2/root2. Kills xw2 dispatch +
//      12.8MB h round-trip. xwk2/xr2 now separate buffers (agg1 writes
//      them while reading xwk1).
//  (b) agg2 re-tiled: 8 slots x 8 lanes, dword 2-ch loads, quad-unroll
//      -> 32 edges in flight (was 16), softmax in 8-lane shfl groups.

#define F_IN   48
#define HID    32
#define NCLS   10
#define KS     4
#define BKT_SH 8               // 256 nodes per bucket
#define TILE   4096            // edges per bucket_scatter block

__device__ inline unsigned short f2bf(float f) {
    unsigned x = __float_as_uint(f);
    unsigned r = x + 0x7FFFu + ((x >> 16) & 1u);  // RNE
    return (unsigned short)(r >> 16);
}
__device__ inline float bf2f(unsigned short u) {
    return __uint_as_float(((unsigned)u) << 16);
}

// ---------- CSR build (bucketed two-level sort, R8 form) ----------

__global__ void bucket_hist_kernel(const int* __restrict__ ei, int* __restrict__ bcnt,
                                   int E, int NB) {
    __shared__ int lcnt[256];
    int t = threadIdx.x;
    lcnt[t] = 0;
    __syncthreads();
    int e0 = blockIdx.x * TILE;
    int n = min(TILE, E - e0);
    for (int r = 0; r < TILE / 256; ++r) {
        int i = r * 256 + t;
        if (i < n) atomicAdd(&lcnt[ei[E + e0 + i] >> BKT_SH], 1);
    }
    __syncthreads();
    if (t < NB && lcnt[t] > 0) atomicAdd(&bcnt[t], lcnt[t]);
}

__global__ void mini_scan_kernel(const int* __restrict__ bcnt, int* __restrict__ bbase,
                                 int* __restrict__ gcur, int NB) {
    __shared__ int a[256], c[256];
    int t = threadIdx.x;
    int v = (t < NB) ? bcnt[t] : 0;
    a[t] = v; c[t] = v;
    __syncthreads();
    for (int o = 1; o < 256; o <<= 1) {
        int w = (t >= o) ? a[t - o] : 0;
        __syncthreads();
        a[t] += w;
        __syncthreads();
    }
    int ex = a[t] - c[t];
    if (t < NB) { bbase[t] = ex; gcur[t] = ex; }
    if (t == 0) bbase[NB] = a[255];
}

__global__ void bucket_scatter_kernel(const int* __restrict__ ei, const float* __restrict__ ea,
                                      int* __restrict__ gcur, uint2* __restrict__ tpd,
                                      int E, int NB) {
    __shared__ unsigned spl[TILE];
    __shared__ unsigned short sdst[TILE];
    __shared__ unsigned short inv[TILE];
    __shared__ int lcnt[256], loff[256], lrank[256], gb[256];
    int t = threadIdx.x;
    lcnt[t] = 0; lrank[t] = 0;
    __syncthreads();
    int e0 = blockIdx.x * TILE;
    int n = min(TILE, E - e0);
    for (int r = 0; r < TILE / 256; ++r) {
        int i = r * 256 + t;
        if (i < n) {
            int e = e0 + i;
            int src = ei[e];
            int dst = ei[E + e];
            float u = ea[e];
            float v = u * (float)(KS - 1);
            float vf = floorf(v);
            int k0 = min(max((int)vf, 0), KS - 1);
            unsigned qf = (unsigned)((v - vf) * 16383.f + 0.5f);  // 14-bit frac
            spl[i] = (unsigned)src | ((unsigned)k0 << 16) | (qf << 18);
            sdst[i] = (unsigned short)dst;
            atomicAdd(&lcnt[dst >> BKT_SH], 1);
        }
    }
    __syncthreads();
    loff[t] = lcnt[t];
    __syncthreads();
    for (int o = 1; o < 256; o <<= 1) {
        int w = (t >= o) ? loff[t - o] : 0;
        __syncthreads();
        loff[t] += w;
        __syncthreads();
    }
    int ex = loff[t] - lcnt[t];
    __syncthreads();
    loff[t] = ex;
    if (t < NB) gb[t] = atomicAdd(&gcur[t], lcnt[t]);
    __syncthreads();
    for (int r = 0; r < TILE / 256; ++r) {
        int i = r * 256 + t;
        if (i < n) {
            int b = sdst[i] >> BKT_SH;
            int p = loff[b] + atomicAdd(&lrank[b], 1);
            inv[p] = (unsigned short)i;
        }
    }
    __syncthreads();
    for (int r = 0; r < TILE / 256; ++r) {
        int j = r * 256 + t;
        if (j < n) {
            int i = inv[j];
            int d = sdst[i];
            int b = d >> BKT_SH;
            int pos = gb[b] + (j - loff[b]);
            tpd[pos] = make_uint2(spl[i], (unsigned)d);
        }
    }
}

__global__ void node_sort_kernel(const uint2* __restrict__ tpd, const int* __restrict__ bbase,
                                 unsigned* __restrict__ spk, int* __restrict__ offs,
                                 int N, int NB) {
    __shared__ int hc[256], hs[256], hr[256];
    int b = blockIdx.x;
    int t = threadIdx.x;
    int nb0 = b << BKT_SH;
    int nb = min(256, N - nb0);
    int base = bbase[b];
    int m = bbase[b + 1] - base;
    hc[t] = 0; hr[t] = 0;
    __syncthreads();
    for (int i = t; i < m; i += 256) atomicAdd(&hc[tpd[base + i].y - nb0], 1);
    __syncthreads();
    hs[t] = hc[t];
    __syncthreads();
    for (int o = 1; o < 256; o <<= 1) {
        int w = (t >= o) ? hs[t - o] : 0;
        __syncthreads();
        hs[t] += w;
        __syncthreads();
    }
    if (t < nb) offs[nb0 + t] = base + (hs[t] - hc[t]);
    if (b == NB - 1 && t == 0) offs[N] = base + m;
    for (int i = t; i < m; i += 256) {
        uint2 rec = tpd[base + i];
        int d = rec.y - nb0;
        int p = (hs[d] - hc[d]) + atomicAdd(&hr[d], 1);
        spk[base + p] = rec.x;
    }
}

// ---------- xw1 table (LDS-staged W, register-blocked) ----------

__global__ __launch_bounds__(320) void xw1_kernel(
        const float* __restrict__ X, const float* __restrict__ W,
        const float* __restrict__ R, unsigned short* __restrict__ outk,
        float* __restrict__ outr, int n) {
    __shared__ float lw[48 * 160];
    int t = threadIdx.x;
    for (int i = t; i < 48 * 160; i += 320) {
        int f = i / 160;
        int col = i - f * 160;
        lw[i] = (col < 128) ? W[(size_t)(col >> 5) * (48 * 32) + f * 32 + (col & 31)]
                            : R[f * 32 + (col - 128)];
    }
    __syncthreads();
    int g = t % 40;      // colgroup (4 cols)
    int lp = t / 40;     // local pair 0..7
    int n0 = (blockIdx.x * 8 + lp) * 2;
    if (n0 + 1 >= n) return;
    const float4* X0 = (const float4*)(X + (size_t)n0 * F_IN);
    const float4* X1 = (const float4*)(X + (size_t)(n0 + 1) * F_IN);
    float4 x0[12], x1[12];
#pragma unroll
    for (int i = 0; i < 12; ++i) { x0[i] = X0[i]; x1[i] = X1[i]; }
    const float4* lw4 = (const float4*)lw;  // lw4[f*40 + g]
    float4 a0 = {0,0,0,0}, a1 = {0,0,0,0};
#pragma unroll
    for (int fb = 0; fb < 12; ++fb) {
        float4 v0 = x0[fb], v1 = x1[fb];
#pragma unroll
        for (int j = 0; j < 4; ++j) {
            float s0 = (j == 0) ? v0.x : (j == 1) ? v0.y : (j == 2) ? v0.z : v0.w;
            float s1 = (j == 0) ? v1.x : (j == 1) ? v1.y : (j == 2) ? v1.z : v1.w;
            float4 w = lw4[(fb * 4 + j) * 40 + g];
            a0.x = fmaf(s0, w.x, a0.x); a0.y = fmaf(s0, w.y, a0.y);
            a0.z = fmaf(s0, w.z, a0.z); a0.w = fmaf(s0, w.w, a0.w);
            a1.x = fmaf(s1, w.x, a1.x); a1.y = fmaf(s1, w.y, a1.y);
            a1.z = fmaf(s1, w.z, a1.z); a1.w = fmaf(s1, w.w, a1.w);
        }
    }
    if (g < 32) {
        uint2 u0, u1;
        u0.x = f2bf(a0.x) | ((unsigned)f2bf(a0.y) << 16);
        u0.y = f2bf(a0.z) | ((unsigned)f2bf(a0.w) << 16);
        u1.x = f2bf(a1.x) | ((unsigned)f2bf(a1.y) << 16);
        u1.y = f2bf(a1.z) | ((unsigned)f2bf(a1.w) << 16);
        *(uint2*)(outk + (size_t)n0 * (KS * HID) + g * 4) = u0;
        *(uint2*)(outk + (size_t)(n0 + 1) * (KS * HID) + g * 4) = u1;
    } else {
        int o = 4 * g - 128;
        *(float4*)(outr + (size_t)n0 * HID + o) = a0;
        *(float4*)(outr + (size_t)(n0 + 1) * HID + o) = a1;
    }
}

// ---------- aggregation ----------

// Decode a packed spline record into a row pointer, k1-k0 offset, frac.
#define DECODE32(p, row, dk, fr)                                          \
    {   int src_ = (p) & 0xFFFF;                                          \
        int k0_ = ((p) >> 16) & 3;                                        \
        int k1_ = min(k0_ + 1, KS - 1);                                   \
        fr = (float)((p) >> 18) * (1.f / 16383.f);                        \
        row = xwk + (size_t)src_ * (KS * HID) + k0_ * HID + cg * 4;       \
        dk = (k1_ - k0_) * HID; }

__device__ inline void fma4(uint2 v0, uint2 v1, float fr, float4& a) {
    float w0 = 1.f - fr;
    a.x = fmaf(w0, __uint_as_float(v0.x << 16), a.x);
    a.x = fmaf(fr, __uint_as_float(v1.x << 16), a.x);
    a.y = fmaf(w0, __uint_as_float(v0.x & 0xFFFF0000u), a.y);
    a.y = fmaf(fr, __uint_as_float(v1.x & 0xFFFF0000u), a.y);
    a.z = fmaf(w0, __uint_as_float(v0.y << 16), a.z);
    a.z = fmaf(fr, __uint_as_float(v1.y << 16), a.z);
    a.w = fmaf(w0, __uint_as_float(v0.y & 0xFFFF0000u), a.w);
    a.w = fmaf(fr, __uint_as_float(v1.y & 0xFFFF0000u), a.w);
}

// agg1 + fused xw2: one wave per node; lane = (slot 0..7, chgroup 0..7).
// Main loop: 32 edges (64 row-gathers) in flight per wave. Epilogue:
// every lane holds 4 h-channels post-reduce -> ELU on all lanes ->
// wave-broadcast h via 32 static shfl -> per-lane dot vs LDS W2/root2.
__global__ void agg1_kernel(const unsigned short* __restrict__ xwk,
                            const float* __restrict__ xroot,
                            const int* __restrict__ offs, const unsigned* __restrict__ spk,
                            const float* __restrict__ bias,
                            const float* __restrict__ W2, const float* __restrict__ R2,
                            unsigned short* __restrict__ outk2, float* __restrict__ outr2,
                            int n) {
    __shared__ float lw2f[32 * 50];
    int t = threadIdx.x;
    for (int i = t; i < 32 * 50; i += 256) {
        int f = i / 50;
        int col = i - f * 50;
        lw2f[i] = (col < 40) ? W2[(size_t)(col / 10) * (32 * 10) + f * 10 + (col % 10)]
                             : R2[f * 10 + (col - 40)];
    }
    __syncthreads();

    int lane = t & 63;
    int cg = lane & 7;       // channels 4cg..4cg+3
    int slot = lane >> 3;    // 8 edge slots
    int node = blockIdx.x * 4 + (t >> 6);
    bool nv = node < n;
    if (!nv) node = n - 1;   // harmless duplicate work, no stores
    int beg = offs[node];
    int end = offs[node + 1];
    float4 a0 = {0, 0, 0, 0}, a1 = {0, 0, 0, 0};
    int e = beg + slot;
    while (e + 24 < end) {
        unsigned p0 = spk[e], p1 = spk[e + 8], p2 = spk[e + 16], p3 = spk[e + 24];
        const unsigned short *r0, *r1, *r2, *r3;
        int d0, d1, d2, d3;
        float f0, f1, f2, f3;
        DECODE32(p0, r0, d0, f0);
        DECODE32(p1, r1, d1, f1);
        DECODE32(p2, r2, d2, f2);
        DECODE32(p3, r3, d3, f3);
        uint2 v00 = *(const uint2*)r0, v01 = *(const uint2*)(r0 + d0);
        uint2 v10 = *(const uint2*)r1, v11 = *(const uint2*)(r1 + d1);
        uint2 v20 = *(const uint2*)r2, v21 = *(const uint2*)(r2 + d2);
        uint2 v30 = *(const uint2*)r3, v31 = *(const uint2*)(r3 + d3);
        fma4(v00, v01, f0, a0);
        fma4(v10, v11, f1, a1);
        fma4(v20, v21, f2, a0);
        fma4(v30, v31, f3, a1);
        e += 32;
    }
    while (e < end) {
        unsigned p = spk[e];
        const unsigned short* r;
        int d;
        float f;
        DECODE32(p, r, d, f);
        uint2 v0 = *(const uint2*)r, v1 = *(const uint2*)(r + d);
        fma4(v0, v1, f, a0);
        e += 8;
    }
    float4 s;
    s.x = a0.x + a1.x; s.y = a0.y + a1.y; s.z = a0.z + a1.z; s.w = a0.w + a1.w;
#pragma unroll
    for (int m = 8; m < 64; m <<= 1) {   // reduce across 8 slots
        s.x += __shfl_xor(s.x, m, 64);
        s.y += __shfl_xor(s.y, m, 64);
        s.z += __shfl_xor(s.z, m, 64);
        s.w += __shfl_xor(s.w, m, 64);
    }
    // all lanes now hold the reduced sums for their cg -> h on all lanes
    int deg = end - beg;
    float invd = 1.f / (float)(deg > 0 ? deg : 1);
    float4 r = *(const float4*)(xroot + (size_t)node * HID + cg * 4);
    float4 b = *(const float4*)(bias + cg * 4);
    float4 o;
    o.x = fmaf(s.x, invd, r.x + b.x);
    o.y = fmaf(s.y, invd, r.y + b.y);
    o.z = fmaf(s.z, invd, r.z + b.z);
    o.w = fmaf(s.w, invd, r.w + b.w);
    o.x = (o.x > 0.f) ? o.x : expm1f(o.x);
    o.y = (o.y > 0.f) ? o.y : expm1f(o.y);
    o.z = (o.z > 0.f) ? o.z : expm1f(o.z);
    o.w = (o.w > 0.f) ? o.w : expm1f(o.w);
    // fused xw2: col = lane (50 active), h broadcast via static shfl
    int col = min(lane, 49);
    int slbase = lane & 56;
    float acc = 0.f;
#pragma unroll
    for (int fg = 0; fg < 8; ++fg) {
        int sl = slbase | fg;
        float h0 = __shfl(o.x, sl, 64);
        float h1 = __shfl(o.y, sl, 64);
        float h2 = __shfl(o.z, sl, 64);
        float h3 = __shfl(o.w, sl, 64);
        acc = fmaf(h0, lw2f[(4 * fg + 0) * 50 + col], acc);
        acc = fmaf(h1, lw2f[(4 * fg + 1) * 50 + col], acc);
        acc = fmaf(h2, lw2f[(4 * fg + 2) * 50 + col], acc);
        acc = fmaf(h3, lw2f[(4 * fg + 3) * 50 + col], acc);
    }
    if (nv && lane < 50) {
        if (col < 40) outk2[(size_t)node * 40 + col] = f2bf(acc);
        else          outr2[(size_t)node * NCLS + (col - 40)] = acc;
    }
}

// agg2: one wave per node; lane = (slot 0..7, pair 0..7; pairs 0..4 active).
// dword loads = 2 bf16 channels; quad-unrolled -> 32 edges in flight.
__global__ void agg2_kernel(const unsigned short* __restrict__ xwk,
                            const float* __restrict__ xroot,
                            const int* __restrict__ offs, const unsigned* __restrict__ spk,
                            const float* __restrict__ bias, float* __restrict__ out, int n) {
    int lane = threadIdx.x & 63;
    int u = lane & 7;        // channel pair (2u, 2u+1); valid u<5
    int slot = lane >> 3;    // 8 edge slots
    int node = blockIdx.x * 4 + (threadIdx.x >> 6);
    bool nv = node < n;
    if (!nv) node = n - 1;
    int up = min(u, 4);
    int beg = offs[node];
    int end = offs[node + 1];
    float a0l = 0.f, a0h = 0.f, a1l = 0.f, a1h = 0.f;

#define DEC2(p, q0, q1, fr)                                               \
    {   int src_ = (p) & 0xFFFF;                                          \
        int k0_ = ((p) >> 16) & 3;                                        \
        int k1_ = min(k0_ + 1, KS - 1);                                   \
        fr = (float)((p) >> 18) * (1.f / 16383.f);                        \
        const unsigned short* row_ = xwk + (size_t)src_ * 40;             \
        q0 = (const unsigned*)(row_ + k0_ * 10) + up;                     \
        q1 = (const unsigned*)(row_ + k1_ * 10) + up; }

#define FMA2(t0, t1, fr, al, ah)                                          \
    {   float w0_ = 1.f - fr;                                             \
        al = fmaf(w0_, __uint_as_float((t0) << 16), al);                  \
        al = fmaf(fr,  __uint_as_float((t1) << 16), al);                  \
        ah = fmaf(w0_, __uint_as_float((t0) & 0xFFFF0000u), ah);          \
        ah = fmaf(fr,  __uint_as_float((t1) & 0xFFFF0000u), ah); }

    int e = beg + slot;
    while (e + 24 < end) {
        unsigned p0 = spk[e], p1 = spk[e + 8], p2 = spk[e + 16], p3 = spk[e + 24];
        const unsigned *q00, *q01, *q10, *q11, *q20, *q21, *q30, *q31;
        float f0, f1, f2, f3;
        DEC2(p0, q00, q01, f0);
        DEC2(p1, q10, q11, f1);
        DEC2(p2, q20, q21, f2);
        DEC2(p3, q30, q31, f3);
        unsigned t00 = *q00, t01 = *q01;
        unsigned t10 = *q10, t11 = *q11;
        unsigned t20 = *q20, t21 = *q21;
        unsigned t30 = *q30, t31 = *q31;
        FMA2(t00, t01, f0, a0l, a0h);
        FMA2(t10, t11, f1, a1l, a1h);
        FMA2(t20, t21, f2, a0l, a0h);
        FMA2(t30, t31, f3, a1l, a1h);
        e += 32;
    }
    while (e < end) {
        unsigned p = spk[e];
        const unsigned *q0, *q1;
        float f;
        DEC2(p, q0, q1, f);
        unsigned t0 = *q0, t1 = *q1;
        FMA2(t0, t1, f, a0l, a0h);
        e += 8;
    }
    float vl = a0l + a1l, vh = a0h + a1h;
    if (u > 4) { vl = 0.f; vh = 0.f; }
#pragma unroll
    for (int m = 8; m < 64; m <<= 1) {   // reduce across 8 slots
        vl += __shfl_xor(vl, m, 64);
        vh += __shfl_xor(vh, m, 64);
    }
    int deg = end - beg;
    float invd = 1.f / (float)(deg > 0 ? deg : 1);
    float l0 = -INFINITY, l1 = -INFINITY;
    if (u < 5) {
        float2 xr = *(const float2*)(xroot + (size_t)node * NCLS + 2 * u);
        l0 = fmaf(vl, invd, xr.x + bias[2 * u]);
        l1 = fmaf(vh, invd, xr.y + bias[2 * u + 1]);
    }
    float mx = fmaxf(l0, l1);
#pragma unroll
    for (int m = 1; m < 8; m <<= 1) mx = fmaxf(mx, __shfl_xor(mx, m, 64));
    float sden = (u < 5) ? (expf(l0 - mx) + expf(l1 - mx)) : 0.f;
#pragma unroll
    for (int m = 1; m < 8; m <<= 1) sden += __shfl_xor(sden, m, 64);
    if (nv && slot == 0 && u < 5) {
        float ls = logf(sden);
        *(float2*)(out + (size_t)node * NCLS + 2 * u) =
            make_float2(l0 - mx - ls, l1 - mx - ls);
    }
}

extern "C" void kernel_launch(void* const* d_in, const int* in_sizes, int n_in,
                              void* d_out, int out_size, void* d_ws, size_t ws_size,
                              hipStream_t stream) {
    const float* x       = (const float*)d_in[0];
    const int*   ei      = (const int*)d_in[1];
    const float* ea      = (const float*)d_in[2];
    const float* W1      = (const float*)d_in[3];
    const float* root1   = (const float*)d_in[4];
    const float* bias1   = (const float*)d_in[5];
    const float* W2      = (const float*)d_in[6];
    const float* root2   = (const float*)d_in[7];
    const float* bias2   = (const float*)d_in[8];
    float* out = (float*)d_out;

    const int N = in_sizes[0] / F_IN;      // 50000
    const int E = in_sizes[2];             // 1600000
    const int NB = (N + 255) >> BKT_SH;    // 196

    char* base = (char*)d_ws;
    size_t off = 0;
    auto alloc = [&](size_t bytes) {
        char* p = base + off;
        off = (off + bytes + 255) & ~(size_t)255;
        return (void*)p;
    };
    unsigned short* xwk1 = (unsigned short*)alloc((size_t)N * KS * HID * 2); // 12.8 MB
    float* xr1           = (float*)alloc((size_t)N * HID * 4);               // 6.4 MB
    unsigned short* xwk2 = (unsigned short*)alloc((size_t)N * 40 * 2);       // 4 MB
    float* xr2           = (float*)alloc((size_t)N * NCLS * 4);              // 2 MB
    int* offs            = (int*)alloc(((size_t)N + 1) * 4);
    int* bcnt            = (int*)alloc((size_t)NB * 4);
    int* bbase           = (int*)alloc(((size_t)NB + 1) * 4);
    int* gcur            = (int*)alloc((size_t)NB * 4);
    unsigned* spk        = (unsigned*)alloc((size_t)E * 4);                  // 6.4 MB
    uint2* tpd           = (uint2*)xwk1;  // 12.8MB, aliases xwk1 (dead before xw1)
    if (ws_size < off) return;

    int ebk = (E + TILE - 1) / TILE;

    hipMemsetAsync(bcnt, 0, (size_t)NB * 4, stream);
    bucket_hist_kernel<<<ebk, 256, 0, stream>>>(ei, bcnt, E, NB);
    mini_scan_kernel<<<1, 256, 0, stream>>>(bcnt, bbase, gcur, NB);
    bucket_scatter_kernel<<<ebk, 256, 0, stream>>>(ei, ea, gcur, tpd, E, NB);
    node_sort_kernel<<<NB, 256, 0, stream>>>(tpd, bbase, spk, offs, N, NB);
    // xw1 after node_sort (tpd aliases xwk1)
    xw1_kernel<<<(N + 15) / 16, 320, 0, stream>>>(x, W1, root1, xwk1, xr1, N);
    agg1_kernel<<<(N + 3) / 4, 256, 0, stream>>>(xwk1, xr1, offs, spk, bias1,
                                                 W2, root2, xwk2, xr2, N);
    agg2_kernel<<<(N + 3) / 4, 256, 0, stream>>>(xwk2, xr2, offs, spk, bias2, out, N);
}

// Round 6
// 247.555 us; speedup vs baseline: 1.5754x; 1.0437x over previous
//
#include <hip/hip_runtime.h>
#include <math.h>

// SplineConv x2 (K=4, dim=1, degree=1, mean aggr) + ELU + log_softmax.
// R12: R11's xw2-into-agg1 fusion regressed agg1 40->65.5us (VALUBusy
// 51->73%): per-block W2 staging with /50 %50 divides + 32 ds_bpermute
// + 32 scalar LDS reads per node cost +25us to save xw2's 5us. Reverted
// to R8's lean agg1 (epilogue on slot==0 only) + separate xw2 kernel.
// KEPT R11's agg2 re-tile (8 slots x 8 ch-pairs, dword 2-ch loads,
// quad-unroll -> 32 edges in flight; ~-12us vs R8 form, inferred from
// the R11 total decomposition). Bucketed CSR build unchanged.

#define F_IN   48
#define HID    32
#define NCLS   10
#define KS     4
#define BKT_SH 8               // 256 nodes per bucket
#define TILE   4096            // edges per bucket_scatter block

__device__ inline unsigned short f2bf(float f) {
    unsigned x = __float_as_uint(f);
    unsigned r = x + 0x7FFFu + ((x >> 16) & 1u);  // RNE
    return (unsigned short)(r >> 16);
}
__device__ inline float bf2f(unsigned short u) {
    return __uint_as_float(((unsigned)u) << 16);
}

// ---------- CSR build (bucketed two-level sort) ----------

__global__ void bucket_hist_kernel(const int* __restrict__ ei, int* __restrict__ bcnt,
                                   int E, int NB) {
    __shared__ int lcnt[256];
    int t = threadIdx.x;
    lcnt[t] = 0;
    __syncthreads();
    int e0 = blockIdx.x * TILE;
    int n = min(TILE, E - e0);
    for (int r = 0; r < TILE / 256; ++r) {
        int i = r * 256 + t;
        if (i < n) atomicAdd(&lcnt[ei[E + e0 + i] >> BKT_SH], 1);
    }
    __syncthreads();
    if (t < NB && lcnt[t] > 0) atomicAdd(&bcnt[t], lcnt[t]);
}

__global__ void mini_scan_kernel(const int* __restrict__ bcnt, int* __restrict__ bbase,
                                 int* __restrict__ gcur, int NB) {
    __shared__ int a[256], c[256];
    int t = threadIdx.x;
    int v = (t < NB) ? bcnt[t] : 0;
    a[t] = v; c[t] = v;
    __syncthreads();
    for (int o = 1; o < 256; o <<= 1) {
        int w = (t >= o) ? a[t - o] : 0;
        __syncthreads();
        a[t] += w;
        __syncthreads();
    }
    int ex = a[t] - c[t];
    if (t < NB) { bbase[t] = ex; gcur[t] = ex; }
    if (t == 0) bbase[NB] = a[255];
}

__global__ void bucket_scatter_kernel(const int* __restrict__ ei, const float* __restrict__ ea,
                                      int* __restrict__ gcur, uint2* __restrict__ tpd,
                                      int E, int NB) {
    __shared__ unsigned spl[TILE];
    __shared__ unsigned short sdst[TILE];
    __shared__ unsigned short inv[TILE];
    __shared__ int lcnt[256], loff[256], lrank[256], gb[256];
    int t = threadIdx.x;
    lcnt[t] = 0; lrank[t] = 0;
    __syncthreads();
    int e0 = blockIdx.x * TILE;
    int n = min(TILE, E - e0);
    for (int r = 0; r < TILE / 256; ++r) {
        int i = r * 256 + t;
        if (i < n) {
            int e = e0 + i;
            int src = ei[e];
            int dst = ei[E + e];
            float u = ea[e];
            float v = u * (float)(KS - 1);
            float vf = floorf(v);
            int k0 = min(max((int)vf, 0), KS - 1);
            unsigned qf = (unsigned)((v - vf) * 16383.f + 0.5f);  // 14-bit frac
            spl[i] = (unsigned)src | ((unsigned)k0 << 16) | (qf << 18);
            sdst[i] = (unsigned short)dst;
            atomicAdd(&lcnt[dst >> BKT_SH], 1);
        }
    }
    __syncthreads();
    loff[t] = lcnt[t];
    __syncthreads();
    for (int o = 1; o < 256; o <<= 1) {
        int w = (t >= o) ? loff[t - o] : 0;
        __syncthreads();
        loff[t] += w;
        __syncthreads();
    }
    int ex = loff[t] - lcnt[t];
    __syncthreads();
    loff[t] = ex;
    if (t < NB) gb[t] = atomicAdd(&gcur[t], lcnt[t]);
    __syncthreads();
    for (int r = 0; r < TILE / 256; ++r) {
        int i = r * 256 + t;
        if (i < n) {
            int b = sdst[i] >> BKT_SH;
            int p = loff[b] + atomicAdd(&lrank[b], 1);
            inv[p] = (unsigned short)i;
        }
    }
    __syncthreads();
    for (int r = 0; r < TILE / 256; ++r) {
        int j = r * 256 + t;
        if (j < n) {
            int i = inv[j];
            int d = sdst[i];
            int b = d >> BKT_SH;
            int pos = gb[b] + (j - loff[b]);
            tpd[pos] = make_uint2(spl[i], (unsigned)d);
        }
    }
}

__global__ void node_sort_kernel(const uint2* __restrict__ tpd, const int* __restrict__ bbase,
                                 unsigned* __restrict__ spk, int* __restrict__ offs,
                                 int N, int NB) {
    __shared__ int hc[256], hs[256], hr[256];
    int b = blockIdx.x;
    int t = threadIdx.x;
    int nb0 = b << BKT_SH;
    int nb = min(256, N - nb0);
    int base = bbase[b];
    int m = bbase[b + 1] - base;
    hc[t] = 0; hr[t] = 0;
    __syncthreads();
    for (int i = t; i < m; i += 256) atomicAdd(&hc[tpd[base + i].y - nb0], 1);
    __syncthreads();
    hs[t] = hc[t];
    __syncthreads();
    for (int o = 1; o < 256; o <<= 1) {
        int w = (t >= o) ? hs[t - o] : 0;
        __syncthreads();
        hs[t] += w;
        __syncthreads();
    }
    if (t < nb) offs[nb0 + t] = base + (hs[t] - hc[t]);
    if (b == NB - 1 && t == 0) offs[N] = base + m;
    for (int i = t; i < m; i += 256) {
        uint2 rec = tpd[base + i];
        int d = rec.y - nb0;
        int p = (hs[d] - hc[d]) + atomicAdd(&hr[d], 1);
        spk[base + p] = rec.x;
    }
}

// ---------- xw tables (LDS-staged W, register-blocked) ----------

__global__ __launch_bounds__(320) void xw1_kernel(
        const float* __restrict__ X, const float* __restrict__ W,
        const float* __restrict__ R, unsigned short* __restrict__ outk,
        float* __restrict__ outr, int n) {
    __shared__ float lw[48 * 160];
    int t = threadIdx.x;
    for (int i = t; i < 48 * 160; i += 320) {
        int f = i / 160;
        int col = i - f * 160;
        lw[i] = (col < 128) ? W[(size_t)(col >> 5) * (48 * 32) + f * 32 + (col & 31)]
                            : R[f * 32 + (col - 128)];
    }
    __syncthreads();
    int g = t % 40;      // colgroup (4 cols)
    int lp = t / 40;     // local pair 0..7
    int n0 = (blockIdx.x * 8 + lp) * 2;
    if (n0 + 1 >= n) return;
    const float4* X0 = (const float4*)(X + (size_t)n0 * F_IN);
    const float4* X1 = (const float4*)(X + (size_t)(n0 + 1) * F_IN);
    float4 x0[12], x1[12];
#pragma unroll
    for (int i = 0; i < 12; ++i) { x0[i] = X0[i]; x1[i] = X1[i]; }
    const float4* lw4 = (const float4*)lw;  // lw4[f*40 + g]
    float4 a0 = {0,0,0,0}, a1 = {0,0,0,0};
#pragma unroll
    for (int fb = 0; fb < 12; ++fb) {
        float4 v0 = x0[fb], v1 = x1[fb];
#pragma unroll
        for (int j = 0; j < 4; ++j) {
            float s0 = (j == 0) ? v0.x : (j == 1) ? v0.y : (j == 2) ? v0.z : v0.w;
            float s1 = (j == 0) ? v1.x : (j == 1) ? v1.y : (j == 2) ? v1.z : v1.w;
            float4 w = lw4[(fb * 4 + j) * 40 + g];
            a0.x = fmaf(s0, w.x, a0.x); a0.y = fmaf(s0, w.y, a0.y);
            a0.z = fmaf(s0, w.z, a0.z); a0.w = fmaf(s0, w.w, a0.w);
            a1.x = fmaf(s1, w.x, a1.x); a1.y = fmaf(s1, w.y, a1.y);
            a1.z = fmaf(s1, w.z, a1.z); a1.w = fmaf(s1, w.w, a1.w);
        }
    }
    if (g < 32) {
        uint2 u0, u1;
        u0.x = f2bf(a0.x) | ((unsigned)f2bf(a0.y) << 16);
        u0.y = f2bf(a0.z) | ((unsigned)f2bf(a0.w) << 16);
        u1.x = f2bf(a1.x) | ((unsigned)f2bf(a1.y) << 16);
        u1.y = f2bf(a1.z) | ((unsigned)f2bf(a1.w) << 16);
        *(uint2*)(outk + (size_t)n0 * (KS * HID) + g * 4) = u0;
        *(uint2*)(outk + (size_t)(n0 + 1) * (KS * HID) + g * 4) = u1;
    } else {
        int o = 4 * g - 128;
        *(float4*)(outr + (size_t)n0 * HID + o) = a0;
        *(float4*)(outr + (size_t)(n0 + 1) * HID + o) = a1;
    }
}

__global__ void xw2_kernel(const float* __restrict__ H, const float* __restrict__ W,
                           const float* __restrict__ R, unsigned short* __restrict__ outk,
                           float* __restrict__ outr, int n) {
    __shared__ float lw2[32 * 50];
    int t = threadIdx.x;
    for (int i = t; i < 32 * 50; i += 256) {
        int f = i / 50;
        int col = i - f * 50;
        lw2[i] = (col < 40) ? W[(size_t)(col / 10) * (32 * 10) + f * 10 + (col % 10)]
                            : R[f * 10 + (col - 40)];
    }
    __syncthreads();
    int total = (n / 2) * 25;
    int id = blockIdx.x * blockDim.x + t;
    if (id >= total) return;
    int p = id % 25;
    int pr = id / 25;
    int n0 = 2 * pr;
    const float4* H0 = (const float4*)(H + (size_t)n0 * HID);
    const float4* H1 = (const float4*)(H + (size_t)(n0 + 1) * HID);
    float4 h0[8], h1[8];
#pragma unroll
    for (int i = 0; i < 8; ++i) { h0[i] = H0[i]; h1[i] = H1[i]; }
    const float2* lwp = (const float2*)lw2;  // lwp[f*25 + p]
    float ax0 = 0.f, ay0 = 0.f, ax1 = 0.f, ay1 = 0.f;
#pragma unroll
    for (int fb = 0; fb < 8; ++fb) {
        float4 v0 = h0[fb], v1 = h1[fb];
#pragma unroll
        for (int j = 0; j < 4; ++j) {
            float s0 = (j == 0) ? v0.x : (j == 1) ? v0.y : (j == 2) ? v0.z : v0.w;
            float s1 = (j == 0) ? v1.x : (j == 1) ? v1.y : (j == 2) ? v1.z : v1.w;
            float2 w = lwp[(fb * 4 + j) * 25 + p];
            ax0 = fmaf(s0, w.x, ax0); ay0 = fmaf(s0, w.y, ay0);
            ax1 = fmaf(s1, w.x, ax1); ay1 = fmaf(s1, w.y, ay1);
        }
    }
    int col = 2 * p;
    if (col < KS * NCLS) {
        *(unsigned*)(outk + (size_t)n0 * (KS * NCLS) + col) =
            f2bf(ax0) | ((unsigned)f2bf(ay0) << 16);
        *(unsigned*)(outk + (size_t)(n0 + 1) * (KS * NCLS) + col) =
            f2bf(ax1) | ((unsigned)f2bf(ay1) << 16);
    } else {
        int o = col - KS * NCLS;
        *(float2*)(outr + (size_t)n0 * NCLS + o) = make_float2(ax0, ay0);
        *(float2*)(outr + (size_t)(n0 + 1) * NCLS + o) = make_float2(ax1, ay1);
    }
}

// ---------- aggregation ----------

// Decode a packed spline record into a row pointer, k1-k0 offset, frac.
#define DECODE32(p, row, dk, fr)                                          \
    {   int src_ = (p) & 0xFFFF;                                          \
        int k0_ = ((p) >> 16) & 3;                                        \
        int k1_ = min(k0_ + 1, KS - 1);                                   \
        fr = (float)((p) >> 18) * (1.f / 16383.f);                        \
        row = xwk + (size_t)src_ * (KS * HID) + k0_ * HID + cg * 4;       \
        dk = (k1_ - k0_) * HID; }

__device__ inline void fma4(uint2 v0, uint2 v1, float fr, float4& a) {
    float w0 = 1.f - fr;
    a.x = fmaf(w0, __uint_as_float(v0.x << 16), a.x);
    a.x = fmaf(fr, __uint_as_float(v1.x << 16), a.x);
    a.y = fmaf(w0, __uint_as_float(v0.x & 0xFFFF0000u), a.y);
    a.y = fmaf(fr, __uint_as_float(v1.x & 0xFFFF0000u), a.y);
    a.z = fmaf(w0, __uint_as_float(v0.y << 16), a.z);
    a.z = fmaf(fr, __uint_as_float(v1.y << 16), a.z);
    a.w = fmaf(w0, __uint_as_float(v0.y & 0xFFFF0000u), a.w);
    a.w = fmaf(fr, __uint_as_float(v1.y & 0xFFFF0000u), a.w);
}

// agg1: one wave per node; lane = (slot 0..7, chgroup 0..7). Quad-unrolled:
// 32 edges (64 row-gathers) in flight per wave.
__global__ void agg1_kernel(const unsigned short* __restrict__ xwk,
                            const float* __restrict__ xroot,
                            const int* __restrict__ offs, const unsigned* __restrict__ spk,
                            const float* __restrict__ bias, float* __restrict__ h, int n) {
    int lane = threadIdx.x & 63;
    int cg = lane & 7;       // channels 4cg..4cg+3
    int slot = lane >> 3;    // 8 edge slots
    int node = blockIdx.x * 4 + (threadIdx.x >> 6);
    if (node >= n) return;
    int beg = offs[node];
    int end = offs[node + 1];
    float4 a0 = {0, 0, 0, 0}, a1 = {0, 0, 0, 0};
    int e = beg + slot;
    while (e + 24 < end) {
        unsigned p0 = spk[e], p1 = spk[e + 8], p2 = spk[e + 16], p3 = spk[e + 24];
        const unsigned short *r0, *r1, *r2, *r3;
        int d0, d1, d2, d3;
        float f0, f1, f2, f3;
        DECODE32(p0, r0, d0, f0);
        DECODE32(p1, r1, d1, f1);
        DECODE32(p2, r2, d2, f2);
        DECODE32(p3, r3, d3, f3);
        uint2 v00 = *(const uint2*)r0, v01 = *(const uint2*)(r0 + d0);
        uint2 v10 = *(const uint2*)r1, v11 = *(const uint2*)(r1 + d1);
        uint2 v20 = *(const uint2*)r2, v21 = *(const uint2*)(r2 + d2);
        uint2 v30 = *(const uint2*)r3, v31 = *(const uint2*)(r3 + d3);
        fma4(v00, v01, f0, a0);
        fma4(v10, v11, f1, a1);
        fma4(v20, v21, f2, a0);
        fma4(v30, v31, f3, a1);
        e += 32;
    }
    while (e < end) {
        unsigned p = spk[e];
        const unsigned short* r;
        int d;
        float f;
        DECODE32(p, r, d, f);
        uint2 v0 = *(const uint2*)r, v1 = *(const uint2*)(r + d);
        fma4(v0, v1, f, a0);
        e += 8;
    }
    float4 s;
    s.x = a0.x + a1.x; s.y = a0.y + a1.y; s.z = a0.z + a1.z; s.w = a0.w + a1.w;
#pragma unroll
    for (int m = 8; m < 64; m <<= 1) {   // reduce across 8 slots
        s.x += __shfl_xor(s.x, m, 64);
        s.y += __shfl_xor(s.y, m, 64);
        s.z += __shfl_xor(s.z, m, 64);
        s.w += __shfl_xor(s.w, m, 64);
    }
    if (slot == 0) {
        int deg = end - beg;
        float inv = 1.f / (float)(deg > 0 ? deg : 1);
        float4 r = *(const float4*)(xroot + (size_t)node * HID + cg * 4);
        float4 b = *(const float4*)(bias + cg * 4);
        float4 o;
        o.x = fmaf(s.x, inv, r.x + b.x);
        o.y = fmaf(s.y, inv, r.y + b.y);
        o.z = fmaf(s.z, inv, r.z + b.z);
        o.w = fmaf(s.w, inv, r.w + b.w);
        o.x = (o.x > 0.f) ? o.x : expm1f(o.x);
        o.y = (o.y > 0.f) ? o.y : expm1f(o.y);
        o.z = (o.z > 0.f) ? o.z : expm1f(o.z);
        o.w = (o.w > 0.f) ? o.w : expm1f(o.w);
        *(float4*)(h + (size_t)node * HID + cg * 4) = o;
    }
}

// agg2: one wave per node; lane = (slot 0..7, pair 0..7; pairs 0..4 active).
// dword loads = 2 bf16 channels; quad-unrolled -> 32 edges in flight.
__global__ void agg2_kernel(const unsigned short* __restrict__ xwk,
                            const float* __restrict__ xroot,
                            const int* __restrict__ offs, const unsigned* __restrict__ spk,
                            const float* __restrict__ bias, float* __restrict__ out, int n) {
    int lane = threadIdx.x & 63;
    int u = lane & 7;        // channel pair (2u, 2u+1); valid u<5
    int slot = lane >> 3;    // 8 edge slots
    int node = blockIdx.x * 4 + (threadIdx.x >> 6);
    bool nv = node < n;
    if (!nv) node = n - 1;
    int up = min(u, 4);
    int beg = offs[node];
    int end = offs[node + 1];
    float a0l = 0.f, a0h = 0.f, a1l = 0.f, a1h = 0.f;

#define DEC2(p, q0, q1, fr)                                               \
    {   int src_ = (p) & 0xFFFF;                                          \
        int k0_ = ((p) >> 16) & 3;                                        \
        int k1_ = min(k0_ + 1, KS - 1);                                   \
        fr = (float)((p) >> 18) * (1.f / 16383.f);                        \
        const unsigned short* row_ = xwk + (size_t)src_ * 40;             \
        q0 = (const unsigned*)(row_ + k0_ * 10) + up;                     \
        q1 = (const unsigned*)(row_ + k1_ * 10) + up; }

#define FMA2(t0, t1, fr, al, ah)                                          \
    {   float w0_ = 1.f - fr;                                             \
        al = fmaf(w0_, __uint_as_float((t0) << 16), al);                  \
        al = fmaf(fr,  __uint_as_float((t1) << 16), al);                  \
        ah = fmaf(w0_, __uint_as_float((t0) & 0xFFFF0000u), ah);          \
        ah = fmaf(fr,  __uint_as_float((t1) & 0xFFFF0000u), ah); }

    int e = beg + slot;
    while (e + 24 < end) {
        unsigned p0 = spk[e], p1 = spk[e + 8], p2 = spk[e + 16], p3 = spk[e + 24];
        const unsigned *q00, *q01, *q10, *q11, *q20, *q21, *q30, *q31;
        float f0, f1, f2, f3;
        DEC2(p0, q00, q01, f0);
        DEC2(p1, q10, q11, f1);
        DEC2(p2, q20, q21, f2);
        DEC2(p3, q30, q31, f3);
        unsigned t00 = *q00, t01 = *q01;
        unsigned t10 = *q10, t11 = *q11;
        unsigned t20 = *q20, t21 = *q21;
        unsigned t30 = *q30, t31 = *q31;
        FMA2(t00, t01, f0, a0l, a0h);
        FMA2(t10, t11, f1, a1l, a1h);
        FMA2(t20, t21, f2, a0l, a0h);
        FMA2(t30, t31, f3, a1l, a1h);
        e += 32;
    }
    while (e < end) {
        unsigned p = spk[e];
        const unsigned *q0, *q1;
        float f;
        DEC2(p, q0, q1, f);
        unsigned t0 = *q0, t1 = *q1;
        FMA2(t0, t1, f, a0l, a0h);
        e += 8;
    }
    float vl = a0l + a1l, vh = a0h + a1h;
    if (u > 4) { vl = 0.f; vh = 0.f; }
#pragma unroll
    for (int m = 8; m < 64; m <<= 1) {   // reduce across 8 slots
        vl += __shfl_xor(vl, m, 64);
        vh += __shfl_xor(vh, m, 64);
    }
    int deg = end - beg;
    float invd = 1.f / (float)(deg > 0 ? deg : 1);
    float l0 = -INFINITY, l1 = -INFINITY;
    if (u < 5) {
        float2 xr = *(const float2*)(xroot + (size_t)node * NCLS + 2 * u);
        l0 = fmaf(vl, invd, xr.x + bias[2 * u]);
        l1 = fmaf(vh, invd, xr.y + bias[2 * u + 1]);
    }
    float mx = fmaxf(l0, l1);
#pragma unroll
    for (int m = 1; m < 8; m <<= 1) mx = fmaxf(mx, __shfl_xor(mx, m, 64));
    float sden = (u < 5) ? (expf(l0 - mx) + expf(l1 - mx)) : 0.f;
#pragma unroll
    for (int m = 1; m < 8; m <<= 1) sden += __shfl_xor(sden, m, 64);
    if (nv && slot == 0 && u < 5) {
        float ls = logf(sden);
        *(float2*)(out + (size_t)node * NCLS + 2 * u) =
            make_float2(l0 - mx - ls, l1 - mx - ls);
    }
}

extern "C" void kernel_launch(void* const* d_in, const int* in_sizes, int n_in,
                              void* d_out, int out_size, void* d_ws, size_t ws_size,
                              hipStream_t stream) {
    const float* x       = (const float*)d_in[0];
    const int*   ei      = (const int*)d_in[1];
    const float* ea      = (const float*)d_in[2];
    const float* W1      = (const float*)d_in[3];
    const float* root1   = (const float*)d_in[4];
    const float* bias1   = (const float*)d_in[5];
    const float* W2      = (const float*)d_in[6];
    const float* root2   = (const float*)d_in[7];
    const float* bias2   = (const float*)d_in[8];
    float* out = (float*)d_out;

    const int N = in_sizes[0] / F_IN;      // 50000
    const int E = in_sizes[2];             // 1600000
    const int NB = (N + 255) >> BKT_SH;    // 196

    char* base = (char*)d_ws;
    size_t off = 0;
    auto alloc = [&](size_t bytes) {
        char* p = base + off;
        off = (off + bytes + 255) & ~(size_t)255;
        return (void*)p;
    };
    unsigned short* xwk1 = (unsigned short*)alloc((size_t)N * KS * HID * 2); // 12.8 MB
    float* xr1           = (float*)alloc((size_t)N * HID * 4);               // 6.4 MB
    float* h             = (float*)alloc((size_t)N * HID * 4);               // 6.4 MB
    int* offs            = (int*)alloc(((size_t)N + 1) * 4);
    int* bcnt            = (int*)alloc((size_t)NB * 4);
    int* bbase           = (int*)alloc(((size_t)NB + 1) * 4);
    int* gcur            = (int*)alloc((size_t)NB * 4);
    unsigned* spk        = (unsigned*)alloc((size_t)E * 4);                  // 6.4 MB
    uint2* tpd           = (uint2*)xwk1;  // aliases xwk1 (dead before xw1)
    unsigned short* xwk2 = xwk1;          // xw2 runs after agg1 -> safe
    float* xr2           = xr1;
    if (ws_size < off) return;

    int ebk = (E + TILE - 1) / TILE;

    hipMemsetAsync(bcnt, 0, (size_t)NB * 4, stream);
    bucket_hist_kernel<<<ebk, 256, 0, stream>>>(ei, bcnt, E, NB);
    mini_scan_kernel<<<1, 256, 0, stream>>>(bcnt, bbase, gcur, NB);
    bucket_scatter_kernel<<<ebk, 256, 0, stream>>>(ei, ea, gcur, tpd, E, NB);
    node_sort_kernel<<<NB, 256, 0, stream>>>(tpd, bbase, spk, offs, N, NB);
    // xw1 after node_sort (tpd aliases xwk1)
    xw1_kernel<<<(N + 15) / 16, 320, 0, stream>>>(x, W1, root1, xwk1, xr1, N);
    agg1_kernel<<<(N + 3) / 4, 256, 0, stream>>>(xwk1, xr1, offs, spk, bias1, h, N);
    {
        int total = (N / 2) * 25;
        xw2_kernel<<<(total + 255) / 256, 256, 0, stream>>>(h, W2, root2, xwk2, xr2, N);
    }
    agg2_kernel<<<(N + 3) / 4, 256, 0, stream>>>(xwk2, xr2, offs, spk, bias2, out, N);
}

// Round 7
// 232.205 us; speedup vs baseline: 1.6795x; 1.0661x over previous
//
#include <hip/hip_runtime.h>
#include <math.h>

// SplineConv x2 (K=4, dim=1, degree=1, mean aggr) + ELU + log_softmax.
// R13: all kernels < fill (44us); remaining mass = serialized medium
// kernels. node_sort runs 196 blocks (0.77/CU, 60+ CUs idle, latency-
// bound) while xw1 (~12us dense FMA) depends only on x/W1 -- so they
// are co-dispatched as one heterogeneous kernel: blocks [0,NB) do
// node_sort, blocks [NB,NB+4167) do a 256-thread xw1 (6 node-pairs/
// block). LDS = union(30KB xw1 / 3KB sort). tpd de-aliased from xwk1
// (xw1 writes xwk1 concurrently with node_sort reading tpd).
// agg1 (R8 form), agg2 (R11 re-tile), xw2, bucketed CSR unchanged.

#define F_IN   48
#define HID    32
#define NCLS   10
#define KS     4
#define BKT_SH 8               // 256 nodes per bucket
#define TILE   4096            // edges per bucket_scatter block

__device__ inline unsigned short f2bf(float f) {
    unsigned x = __float_as_uint(f);
    unsigned r = x + 0x7FFFu + ((x >> 16) & 1u);  // RNE
    return (unsigned short)(r >> 16);
}
__device__ inline float bf2f(unsigned short u) {
    return __uint_as_float(((unsigned)u) << 16);
}

// ---------- CSR build (bucketed two-level sort) ----------

__global__ void bucket_hist_kernel(const int* __restrict__ ei, int* __restrict__ bcnt,
                                   int E, int NB) {
    __shared__ int lcnt[256];
    int t = threadIdx.x;
    lcnt[t] = 0;
    __syncthreads();
    int e0 = blockIdx.x * TILE;
    int n = min(TILE, E - e0);
    for (int r = 0; r < TILE / 256; ++r) {
        int i = r * 256 + t;
        if (i < n) atomicAdd(&lcnt[ei[E + e0 + i] >> BKT_SH], 1);
    }
    __syncthreads();
    if (t < NB && lcnt[t] > 0) atomicAdd(&bcnt[t], lcnt[t]);
}

__global__ void mini_scan_kernel(const int* __restrict__ bcnt, int* __restrict__ bbase,
                                 int* __restrict__ gcur, int NB) {
    __shared__ int a[256], c[256];
    int t = threadIdx.x;
    int v = (t < NB) ? bcnt[t] : 0;
    a[t] = v; c[t] = v;
    __syncthreads();
    for (int o = 1; o < 256; o <<= 1) {
        int w = (t >= o) ? a[t - o] : 0;
        __syncthreads();
        a[t] += w;
        __syncthreads();
    }
    int ex = a[t] - c[t];
    if (t < NB) { bbase[t] = ex; gcur[t] = ex; }
    if (t == 0) bbase[NB] = a[255];
}

__global__ void bucket_scatter_kernel(const int* __restrict__ ei, const float* __restrict__ ea,
                                      int* __restrict__ gcur, uint2* __restrict__ tpd,
                                      int E, int NB) {
    __shared__ unsigned spl[TILE];
    __shared__ unsigned short sdst[TILE];
    __shared__ unsigned short inv[TILE];
    __shared__ int lcnt[256], loff[256], lrank[256], gb[256];
    int t = threadIdx.x;
    lcnt[t] = 0; lrank[t] = 0;
    __syncthreads();
    int e0 = blockIdx.x * TILE;
    int n = min(TILE, E - e0);
    for (int r = 0; r < TILE / 256; ++r) {
        int i = r * 256 + t;
        if (i < n) {
            int e = e0 + i;
            int src = ei[e];
            int dst = ei[E + e];
            float u = ea[e];
            float v = u * (float)(KS - 1);
            float vf = floorf(v);
            int k0 = min(max((int)vf, 0), KS - 1);
            unsigned qf = (unsigned)((v - vf) * 16383.f + 0.5f);  // 14-bit frac
            spl[i] = (unsigned)src | ((unsigned)k0 << 16) | (qf << 18);
            sdst[i] = (unsigned short)dst;
            atomicAdd(&lcnt[dst >> BKT_SH], 1);
        }
    }
    __syncthreads();
    loff[t] = lcnt[t];
    __syncthreads();
    for (int o = 1; o < 256; o <<= 1) {
        int w = (t >= o) ? loff[t - o] : 0;
        __syncthreads();
        loff[t] += w;
        __syncthreads();
    }
    int ex = loff[t] - lcnt[t];
    __syncthreads();
    loff[t] = ex;
    if (t < NB) gb[t] = atomicAdd(&gcur[t], lcnt[t]);
    __syncthreads();
    for (int r = 0; r < TILE / 256; ++r) {
        int i = r * 256 + t;
        if (i < n) {
            int b = sdst[i] >> BKT_SH;
            int p = loff[b] + atomicAdd(&lrank[b], 1);
            inv[p] = (unsigned short)i;
        }
    }
    __syncthreads();
    for (int r = 0; r < TILE / 256; ++r) {
        int j = r * 256 + t;
        if (j < n) {
            int i = inv[j];
            int d = sdst[i];
            int b = d >> BKT_SH;
            int pos = gb[b] + (j - loff[b]);
            tpd[pos] = make_uint2(spl[i], (unsigned)d);
        }
    }
}

// ---------- fused node_sort + xw1 (heterogeneous blocks) ----------
// Blocks [0,NB): per-bucket node sort (tpd -> spk, offs).
// Blocks [NB, NB+XB): xw1 table build, 256 threads = 40 colgroups x 6
// node-pairs (12 nodes/block). Independent inputs/outputs -> safe co-run.

__global__ __launch_bounds__(256) void nsort_xw1_kernel(
        const uint2* __restrict__ tpd, const int* __restrict__ bbase,
        unsigned* __restrict__ spk, int* __restrict__ offs, int N, int NB,
        const float* __restrict__ X, const float* __restrict__ W,
        const float* __restrict__ R, unsigned short* __restrict__ outk,
        float* __restrict__ outr) {
    __shared__ union {
        struct { int hc[256]; int hs[256]; int hr[256]; } ns;
        float lw[48 * 160];
    } sm;
    int t = threadIdx.x;
    if ((int)blockIdx.x < NB) {
        // ---- node_sort part ----
        int b = blockIdx.x;
        int nb0 = b << BKT_SH;
        int nb = min(256, N - nb0);
        int base = bbase[b];
        int m = bbase[b + 1] - base;
        sm.ns.hc[t] = 0; sm.ns.hr[t] = 0;
        __syncthreads();
        for (int i = t; i < m; i += 256) atomicAdd(&sm.ns.hc[tpd[base + i].y - nb0], 1);
        __syncthreads();
        sm.ns.hs[t] = sm.ns.hc[t];
        __syncthreads();
        for (int o = 1; o < 256; o <<= 1) {
            int w = (t >= o) ? sm.ns.hs[t - o] : 0;
            __syncthreads();
            sm.ns.hs[t] += w;
            __syncthreads();
        }
        if (t < nb) offs[nb0 + t] = base + (sm.ns.hs[t] - sm.ns.hc[t]);
        if (b == NB - 1 && t == 0) offs[N] = base + m;
        for (int i = t; i < m; i += 256) {
            uint2 rec = tpd[base + i];
            int d = rec.y - nb0;
            int p = (sm.ns.hs[d] - sm.ns.hc[d]) + atomicAdd(&sm.ns.hr[d], 1);
            spk[base + p] = rec.x;
        }
        return;
    }
    // ---- xw1 part ----
    int bx = blockIdx.x - NB;
    for (int i = t; i < 48 * 160; i += 256) {
        int f = i / 160;
        int col = i - f * 160;
        sm.lw[i] = (col < 128) ? W[(size_t)(col >> 5) * (48 * 32) + f * 32 + (col & 31)]
                               : R[f * 32 + (col - 128)];
    }
    __syncthreads();
    int g = t % 40;      // colgroup (4 cols)
    int lp = t / 40;     // local pair 0..5 (lp 6 = idle tail threads)
    if (lp >= 6) return;
    int n0 = (bx * 6 + lp) * 2;
    if (n0 + 1 >= N) return;
    const float4* X0 = (const float4*)(X + (size_t)n0 * F_IN);
    const float4* X1 = (const float4*)(X + (size_t)(n0 + 1) * F_IN);
    float4 x0[12], x1[12];
#pragma unroll
    for (int i = 0; i < 12; ++i) { x0[i] = X0[i]; x1[i] = X1[i]; }
    const float4* lw4 = (const float4*)sm.lw;  // lw4[f*40 + g]
    float4 a0 = {0,0,0,0}, a1 = {0,0,0,0};
#pragma unroll
    for (int fb = 0; fb < 12; ++fb) {
        float4 v0 = x0[fb], v1 = x1[fb];
#pragma unroll
        for (int j = 0; j < 4; ++j) {
            float s0 = (j == 0) ? v0.x : (j == 1) ? v0.y : (j == 2) ? v0.z : v0.w;
            float s1 = (j == 0) ? v1.x : (j == 1) ? v1.y : (j == 2) ? v1.z : v1.w;
            float4 w = lw4[(fb * 4 + j) * 40 + g];
            a0.x = fmaf(s0, w.x, a0.x); a0.y = fmaf(s0, w.y, a0.y);
            a0.z = fmaf(s0, w.z, a0.z); a0.w = fmaf(s0, w.w, a0.w);
            a1.x = fmaf(s1, w.x, a1.x); a1.y = fmaf(s1, w.y, a1.y);
            a1.z = fmaf(s1, w.z, a1.z); a1.w = fmaf(s1, w.w, a1.w);
        }
    }
    if (g < 32) {
        uint2 u0, u1;
        u0.x = f2bf(a0.x) | ((unsigned)f2bf(a0.y) << 16);
        u0.y = f2bf(a0.z) | ((unsigned)f2bf(a0.w) << 16);
        u1.x = f2bf(a1.x) | ((unsigned)f2bf(a1.y) << 16);
        u1.y = f2bf(a1.z) | ((unsigned)f2bf(a1.w) << 16);
        *(uint2*)(outk + (size_t)n0 * (KS * HID) + g * 4) = u0;
        *(uint2*)(outk + (size_t)(n0 + 1) * (KS * HID) + g * 4) = u1;
    } else {
        int o = 4 * g - 128;
        *(float4*)(outr + (size_t)n0 * HID + o) = a0;
        *(float4*)(outr + (size_t)(n0 + 1) * HID + o) = a1;
    }
}

__global__ void xw2_kernel(const float* __restrict__ H, const float* __restrict__ W,
                           const float* __restrict__ R, unsigned short* __restrict__ outk,
                           float* __restrict__ outr, int n) {
    __shared__ float lw2[32 * 50];
    int t = threadIdx.x;
    for (int i = t; i < 32 * 50; i += 256) {
        int f = i / 50;
        int col = i - f * 50;
        lw2[i] = (col < 40) ? W[(size_t)(col / 10) * (32 * 10) + f * 10 + (col % 10)]
                            : R[f * 10 + (col - 40)];
    }
    __syncthreads();
    int total = (n / 2) * 25;
    int id = blockIdx.x * blockDim.x + t;
    if (id >= total) return;
    int p = id % 25;
    int pr = id / 25;
    int n0 = 2 * pr;
    const float4* H0 = (const float4*)(H + (size_t)n0 * HID);
    const float4* H1 = (const float4*)(H + (size_t)(n0 + 1) * HID);
    float4 h0[8], h1[8];
#pragma unroll
    for (int i = 0; i < 8; ++i) { h0[i] = H0[i]; h1[i] = H1[i]; }
    const float2* lwp = (const float2*)lw2;  // lwp[f*25 + p]
    float ax0 = 0.f, ay0 = 0.f, ax1 = 0.f, ay1 = 0.f;
#pragma unroll
    for (int fb = 0; fb < 8; ++fb) {
        float4 v0 = h0[fb], v1 = h1[fb];
#pragma unroll
        for (int j = 0; j < 4; ++j) {
            float s0 = (j == 0) ? v0.x : (j == 1) ? v0.y : (j == 2) ? v0.z : v0.w;
            float s1 = (j == 0) ? v1.x : (j == 1) ? v1.y : (j == 2) ? v1.z : v1.w;
            float2 w = lwp[(fb * 4 + j) * 25 + p];
            ax0 = fmaf(s0, w.x, ax0); ay0 = fmaf(s0, w.y, ay0);
            ax1 = fmaf(s1, w.x, ax1); ay1 = fmaf(s1, w.y, ay1);
        }
    }
    int col = 2 * p;
    if (col < KS * NCLS) {
        *(unsigned*)(outk + (size_t)n0 * (KS * NCLS) + col) =
            f2bf(ax0) | ((unsigned)f2bf(ay0) << 16);
        *(unsigned*)(outk + (size_t)(n0 + 1) * (KS * NCLS) + col) =
            f2bf(ax1) | ((unsigned)f2bf(ay1) << 16);
    } else {
        int o = col - KS * NCLS;
        *(float2*)(outr + (size_t)n0 * NCLS + o) = make_float2(ax0, ay0);
        *(float2*)(outr + (size_t)(n0 + 1) * NCLS + o) = make_float2(ax1, ay1);
    }
}

// ---------- aggregation ----------

// Decode a packed spline record into a row pointer, k1-k0 offset, frac.
#define DECODE32(p, row, dk, fr)                                          \
    {   int src_ = (p) & 0xFFFF;                                          \
        int k0_ = ((p) >> 16) & 3;                                        \
        int k1_ = min(k0_ + 1, KS - 1);                                   \
        fr = (float)((p) >> 18) * (1.f / 16383.f);                        \
        row = xwk + (size_t)src_ * (KS * HID) + k0_ * HID + cg * 4;       \
        dk = (k1_ - k0_) * HID; }

__device__ inline void fma4(uint2 v0, uint2 v1, float fr, float4& a) {
    float w0 = 1.f - fr;
    a.x = fmaf(w0, __uint_as_float(v0.x << 16), a.x);
    a.x = fmaf(fr, __uint_as_float(v1.x << 16), a.x);
    a.y = fmaf(w0, __uint_as_float(v0.x & 0xFFFF0000u), a.y);
    a.y = fmaf(fr, __uint_as_float(v1.x & 0xFFFF0000u), a.y);
    a.z = fmaf(w0, __uint_as_float(v0.y << 16), a.z);
    a.z = fmaf(fr, __uint_as_float(v1.y << 16), a.z);
    a.w = fmaf(w0, __uint_as_float(v0.y & 0xFFFF0000u), a.w);
    a.w = fmaf(fr, __uint_as_float(v1.y & 0xFFFF0000u), a.w);
}

// agg1: one wave per node; lane = (slot 0..7, chgroup 0..7). Quad-unrolled:
// 32 edges (64 row-gathers) in flight per wave.
__global__ void agg1_kernel(const unsigned short* __restrict__ xwk,
                            const float* __restrict__ xroot,
                            const int* __restrict__ offs, const unsigned* __restrict__ spk,
                            const float* __restrict__ bias, float* __restrict__ h, int n) {
    int lane = threadIdx.x & 63;
    int cg = lane & 7;       // channels 4cg..4cg+3
    int slot = lane >> 3;    // 8 edge slots
    int node = blockIdx.x * 4 + (threadIdx.x >> 6);
    if (node >= n) return;
    int beg = offs[node];
    int end = offs[node + 1];
    float4 a0 = {0, 0, 0, 0}, a1 = {0, 0, 0, 0};
    int e = beg + slot;
    while (e + 24 < end) {
        unsigned p0 = spk[e], p1 = spk[e + 8], p2 = spk[e + 16], p3 = spk[e + 24];
        const unsigned short *r0, *r1, *r2, *r3;
        int d0, d1, d2, d3;
        float f0, f1, f2, f3;
        DECODE32(p0, r0, d0, f0);
        DECODE32(p1, r1, d1, f1);
        DECODE32(p2, r2, d2, f2);
        DECODE32(p3, r3, d3, f3);
        uint2 v00 = *(const uint2*)r0, v01 = *(const uint2*)(r0 + d0);
        uint2 v10 = *(const uint2*)r1, v11 = *(const uint2*)(r1 + d1);
        uint2 v20 = *(const uint2*)r2, v21 = *(const uint2*)(r2 + d2);
        uint2 v30 = *(const uint2*)r3, v31 = *(const uint2*)(r3 + d3);
        fma4(v00, v01, f0, a0);
        fma4(v10, v11, f1, a1);
        fma4(v20, v21, f2, a0);
        fma4(v30, v31, f3, a1);
        e += 32;
    }
    while (e < end) {
        unsigned p = spk[e];
        const unsigned short* r;
        int d;
        float f;
        DECODE32(p, r, d, f);
        uint2 v0 = *(const uint2*)r, v1 = *(const uint2*)(r + d);
        fma4(v0, v1, f, a0);
        e += 8;
    }
    float4 s;
    s.x = a0.x + a1.x; s.y = a0.y + a1.y; s.z = a0.z + a1.z; s.w = a0.w + a1.w;
#pragma unroll
    for (int m = 8; m < 64; m <<= 1) {   // reduce across 8 slots
        s.x += __shfl_xor(s.x, m, 64);
        s.y += __shfl_xor(s.y, m, 64);
        s.z += __shfl_xor(s.z, m, 64);
        s.w += __shfl_xor(s.w, m, 64);
    }
    if (slot == 0) {
        int deg = end - beg;
        float inv = 1.f / (float)(deg > 0 ? deg : 1);
        float4 r = *(const float4*)(xroot + (size_t)node * HID + cg * 4);
        float4 b = *(const float4*)(bias + cg * 4);
        float4 o;
        o.x = fmaf(s.x, inv, r.x + b.x);
        o.y = fmaf(s.y, inv, r.y + b.y);
        o.z = fmaf(s.z, inv, r.z + b.z);
        o.w = fmaf(s.w, inv, r.w + b.w);
        o.x = (o.x > 0.f) ? o.x : expm1f(o.x);
        o.y = (o.y > 0.f) ? o.y : expm1f(o.y);
        o.z = (o.z > 0.f) ? o.z : expm1f(o.z);
        o.w = (o.w > 0.f) ? o.w : expm1f(o.w);
        *(float4*)(h + (size_t)node * HID + cg * 4) = o;
    }
}

// agg2: one wave per node; lane = (slot 0..7, pair 0..7; pairs 0..4 active).
// dword loads = 2 bf16 channels; quad-unrolled -> 32 edges in flight.
__global__ void agg2_kernel(const unsigned short* __restrict__ xwk,
                            const float* __restrict__ xroot,
                            const int* __restrict__ offs, const unsigned* __restrict__ spk,
                            const float* __restrict__ bias, float* __restrict__ out, int n) {
    int lane = threadIdx.x & 63;
    int u = lane & 7;        // channel pair (2u, 2u+1); valid u<5
    int slot = lane >> 3;    // 8 edge slots
    int node = blockIdx.x * 4 + (threadIdx.x >> 6);
    bool nv = node < n;
    if (!nv) node = n - 1;
    int up = min(u, 4);
    int beg = offs[node];
    int end = offs[node + 1];
    float a0l = 0.f, a0h = 0.f, a1l = 0.f, a1h = 0.f;

#define DEC2(p, q0, q1, fr)                                               \
    {   int src_ = (p) & 0xFFFF;                                          \
        int k0_ = ((p) >> 16) & 3;                                        \
        int k1_ = min(k0_ + 1, KS - 1);                                   \
        fr = (float)((p) >> 18) * (1.f / 16383.f);                        \
        const unsigned short* row_ = xwk + (size_t)src_ * 40;             \
        q0 = (const unsigned*)(row_ + k0_ * 10) + up;                     \
        q1 = (const unsigned*)(row_ + k1_ * 10) + up; }

#define FMA2(t0, t1, fr, al, ah)                                          \
    {   float w0_ = 1.f - fr;                                             \
        al = fmaf(w0_, __uint_as_float((t0) << 16), al);                  \
        al = fmaf(fr,  __uint_as_float((t1) << 16), al);                  \
        ah = fmaf(w0_, __uint_as_float((t0) & 0xFFFF0000u), ah);          \
        ah = fmaf(fr,  __uint_as_float((t1) & 0xFFFF0000u), ah); }

    int e = beg + slot;
    while (e + 24 < end) {
        unsigned p0 = spk[e], p1 = spk[e + 8], p2 = spk[e + 16], p3 = spk[e + 24];
        const unsigned *q00, *q01, *q10, *q11, *q20, *q21, *q30, *q31;
        float f0, f1, f2, f3;
        DEC2(p0, q00, q01, f0);
        DEC2(p1, q10, q11, f1);
        DEC2(p2, q20, q21, f2);
        DEC2(p3, q30, q31, f3);
        unsigned t00 = *q00, t01 = *q01;
        unsigned t10 = *q10, t11 = *q11;
        unsigned t20 = *q20, t21 = *q21;
        unsigned t30 = *q30, t31 = *q31;
        FMA2(t00, t01, f0, a0l, a0h);
        FMA2(t10, t11, f1, a1l, a1h);
        FMA2(t20, t21, f2, a0l, a0h);
        FMA2(t30, t31, f3, a1l, a1h);
        e += 32;
    }
    while (e < end) {
        unsigned p = spk[e];
        const unsigned *q0, *q1;
        float f;
        DEC2(p, q0, q1, f);
        unsigned t0 = *q0, t1 = *q1;
        FMA2(t0, t1, f, a0l, a0h);
        e += 8;
    }
    float vl = a0l + a1l, vh = a0h + a1h;
    if (u > 4) { vl = 0.f; vh = 0.f; }
#pragma unroll
    for (int m = 8; m < 64; m <<= 1) {   // reduce across 8 slots
        vl += __shfl_xor(vl, m, 64);
        vh += __shfl_xor(vh, m, 64);
    }
    int deg = end - beg;
    float invd = 1.f / (float)(deg > 0 ? deg : 1);
    float l0 = -INFINITY, l1 = -INFINITY;
    if (u < 5) {
        float2 xr = *(const float2*)(xroot + (size_t)node * NCLS + 2 * u);
        l0 = fmaf(vl, invd, xr.x + bias[2 * u]);
        l1 = fmaf(vh, invd, xr.y + bias[2 * u + 1]);
    }
    float mx = fmaxf(l0, l1);
#pragma unroll
    for (int m = 1; m < 8; m <<= 1) mx = fmaxf(mx, __shfl_xor(mx, m, 64));
    float sden = (u < 5) ? (expf(l0 - mx) + expf(l1 - mx)) : 0.f;
#pragma unroll
    for (int m = 1; m < 8; m <<= 1) sden += __shfl_xor(sden, m, 64);
    if (nv && slot == 0 && u < 5) {
        float ls = logf(sden);
        *(float2*)(out + (size_t)node * NCLS + 2 * u) =
            make_float2(l0 - mx - ls, l1 - mx - ls);
    }
}

extern "C" void kernel_launch(void* const* d_in, const int* in_sizes, int n_in,
                              void* d_out, int out_size, void* d_ws, size_t ws_size,
                              hipStream_t stream) {
    const float* x       = (const float*)d_in[0];
    const int*   ei      = (const int*)d_in[1];
    const float* ea      = (const float*)d_in[2];
    const float* W1      = (const float*)d_in[3];
    const float* root1   = (const float*)d_in[4];
    const float* bias1   = (const float*)d_in[5];
    const float* W2      = (const float*)d_in[6];
    const float* root2   = (const float*)d_in[7];
    const float* bias2   = (const float*)d_in[8];
    float* out = (float*)d_out;

    const int N = in_sizes[0] / F_IN;      // 50000
    const int E = in_sizes[2];             // 1600000
    const int NB = (N + 255) >> BKT_SH;    // 196

    char* base = (char*)d_ws;
    size_t off = 0;
    auto alloc = [&](size_t bytes) {
        char* p = base + off;
        off = (off + bytes + 255) & ~(size_t)255;
        return (void*)p;
    };
    unsigned short* xwk1 = (unsigned short*)alloc((size_t)N * KS * HID * 2); // 12.8 MB
    float* xr1           = (float*)alloc((size_t)N * HID * 4);               // 6.4 MB
    float* h             = (float*)alloc((size_t)N * HID * 4);               // 6.4 MB
    int* offs            = (int*)alloc(((size_t)N + 1) * 4);
    int* bcnt            = (int*)alloc((size_t)NB * 4);
    int* bbase           = (int*)alloc(((size_t)NB + 1) * 4);
    int* gcur            = (int*)alloc((size_t)NB * 4);
    unsigned* spk        = (unsigned*)alloc((size_t)E * 4);                  // 6.4 MB
    uint2* tpd           = (uint2*)alloc((size_t)E * 8);                     // 12.8 MB (own buffer:
                                          // xw1 writes xwk1 concurrently with node_sort reading tpd)
    unsigned short* xwk2 = xwk1;          // xw2 runs after agg1 -> safe
    float* xr2           = xr1;
    if (ws_size < off) return;

    int ebk = (E + TILE - 1) / TILE;
    int xb  = (N + 11) / 12;               // xw1 blocks (12 nodes each)

    hipMemsetAsync(bcnt, 0, (size_t)NB * 4, stream);
    bucket_hist_kernel<<<ebk, 256, 0, stream>>>(ei, bcnt, E, NB);
    mini_scan_kernel<<<1, 256, 0, stream>>>(bcnt, bbase, gcur, NB);
    bucket_scatter_kernel<<<ebk, 256, 0, stream>>>(ei, ea, gcur, tpd, E, NB);
    nsort_xw1_kernel<<<NB + xb, 256, 0, stream>>>(tpd, bbase, spk, offs, N, NB,
                                                  x, W1, root1, xwk1, xr1);
    agg1_kernel<<<(N + 3) / 4, 256, 0, stream>>>(xwk1, xr1, offs, spk, bias1, h, N);
    {
        int total = (N / 2) * 25;
        xw2_kernel<<<(total + 255) / 256, 256, 0, stream>>>(h, W2, root2, xwk2, xr2, N);
    }
    agg2_kernel<<<(N + 3) / 4, 256, 0, stream>>>(xwk2, xr2, offs, spk, bias2, out, N);
}